// Round 7
// baseline (180.656 us; speedup 1.0000x reference)
//
#include <hip/hip_runtime.h>
#include <stdint.h>

#define M_ROWS 8192
#define C_DIM  512
#define K_CODES 8192

// ws layout:
//   best   : u64[8192]       @ 0
//   cnhalf : f32[8192]       @ 65536
//   count  : u32[8192]       @ 98304
//   lpart  : f32[2048]       @ 131072     (zero region = 139264 B = 17408 u64)
//   A2     : bf16[8192][512] @ 1048576    (X_hi), 8 MB
//   BT     : bf16[8192][512] @ 9437184    (E^T_hi), 8 MB
#define WS_BEST     0
#define WS_CNHALF   65536
#define WS_COUNT    98304
#define WS_LPART    131072
#define WS_ZERO_U64 17408
#define WS_A2       1048576
#define WS_BT       9437184

typedef __attribute__((ext_vector_type(8))) short short8_t;
typedef __attribute__((ext_vector_type(4))) float f32x4;

__device__ __forceinline__ short f32_to_bf16_rne(float v) {
    uint32_t u = __float_as_uint(v);
    uint32_t r = (u + 0x7FFFu + ((u >> 16) & 1u)) >> 16;
    return (short)r;
}
__device__ __forceinline__ float bf16_to_f32(short s) {
    return __uint_as_float(((uint32_t)(uint16_t)s) << 16);
}
__device__ __forceinline__ uint32_t sortable_key(float f) {
    uint32_t b = __float_as_uint(f);
    return ((int)b >= 0) ? (b | 0x80000000u) : ~b;
}

// ---------------- prep: fused conv_x (+ws zero) | conv_e | colnorm ----------------
__global__ __launch_bounds__(256) void vq_prep(const float* __restrict__ x,
                                               const float* __restrict__ emb,
                                               short* __restrict__ A2,
                                               short* __restrict__ BT,
                                               float* __restrict__ cnhalf,
                                               unsigned long long* __restrict__ wszero) {
    __shared__ float t[64][65];
    const int bid = blockIdx.x;
    const int tid = threadIdx.x;
    if (bid < 4096) {
        int idx = bid * 256 + tid;
        if (idx < WS_ZERO_U64) wszero[idx] = 0ull;
        int m = idx >> 7;
        int c4 = (idx & 127) * 4;
        float4 v = *(const float4*)&x[(size_t)m * C_DIM + c4];
        short hi[4] = {f32_to_bf16_rne(v.x), f32_to_bf16_rne(v.y),
                       f32_to_bf16_rne(v.z), f32_to_bf16_rne(v.w)};
        *(short4*)&A2[(size_t)m * 512 + c4] = *(short4*)hi;
    } else if (bid < 5120) {
        int r = bid - 4096;
        int nb = (r & 127) * 64;
        int cb = (r >> 7) * 64;
        #pragma unroll
        for (int i = 0; i < 16; ++i) {
            int c = (tid >> 6) + i * 4;
            t[c][tid & 63] = emb[(size_t)(cb + c) * K_CODES + nb + (tid & 63)];
        }
        __syncthreads();
        const int n = tid >> 2;
        const int cp = (tid & 3) * 16;
        short hibuf[16];
        #pragma unroll
        for (int i = 0; i < 16; ++i) hibuf[i] = f32_to_bf16_rne(t[cp + i][n]);
        size_t base = (size_t)(nb + n) * 512 + cb + cp;
        *(short8_t*)&BT[base + 0] = *(short8_t*)&hibuf[0];
        *(short8_t*)&BT[base + 8] = *(short8_t*)&hibuf[8];
    } else {
        int k = (bid - 5120) * 256 + tid;
        float s = 0.f;
        for (int c = 0; c < C_DIM; ++c) {
            float v = emb[(size_t)c * K_CODES + k];
            s = fmaf(v, v, s);
        }
        cnhalf[k] = 0.5f * s;
    }
}

// ---------------- MFMA score GEMM: 256x1024 per block (4 col-tiles), 8 waves (2x4),
// per-wave 128x64, BK=32, ring-4 LDS, cross-step fragment pipeline:
//   iter g: stage(g+3); vmcnt(8); lgkmcnt(0); barrier; ds_read frags(g+1); MFMA(g)
// -> frag reads of g+1 fly UNDER the MFMAs of g (compiler emits lgkmcnt(12)).
// Slot-reuse proof: reads of slot (g+3)&3 (= tile g-1) were drained by lgkmcnt
// before the PREVIOUS barrier; the stage(g+3) write returns only after it.
// LDS 16B-slot swizzle (R4-R6 verified, 0 conflicts): q = (row*4+s) ^ ((row>>1)&3);
// inverse on global source: row = q>>2, s = (q&3)^((q>>3)&3).
#define WAITV8() asm volatile("s_waitcnt vmcnt(8)" ::: "memory")
#define WAITV4() asm volatile("s_waitcnt vmcnt(4)" ::: "memory")
#define WAITV0() asm volatile("s_waitcnt vmcnt(0)" ::: "memory")
#define LGKM0()  asm volatile("s_waitcnt lgkmcnt(0)" ::: "memory")
#define BAR()    __builtin_amdgcn_s_barrier()

__global__ __launch_bounds__(512, 2) void vq_mfma_argmax(
        const short* __restrict__ A2, const short* __restrict__ BT,
        const float* __restrict__ cnhalf, unsigned long long* __restrict__ best) {
    __shared__ short lds[65536];   // 4 slots x (A[256][32] | B[256][32]) = 128 KiB

    const int tid  = threadIdx.x;
    const int lane = tid & 63;
    const int w    = tid >> 6;
    const int wr   = w >> 2;        // 0..1: 128-row half
    const int wc   = w & 3;         // 0..3: 64-col quarter
    const int l15  = lane & 15;
    const int l4   = lane >> 4;

    const int colg0 = blockIdx.x * 1024;  // blk%8 == col-group -> B-panel pinned per XCD L2
    const int row0  = blockIdx.y * 256;

    // staging source pointers (inverse-swizzled)
    const short* aSrc[2];
    const short* bSrc[2];
    #pragma unroll
    for (int c = 0; c < 2; ++c) {
        int q = c * 512 + tid;
        int row = q >> 2;
        int s = (q & 3) ^ ((q >> 3) & 3);
        aSrc[c] = A2 + (size_t)(row0 + row) * 512 + s * 8;
        bSrc[c] = BT + (size_t)(colg0 + row) * 512 + s * 8;
    }

    // swizzled ds_read byte offsets (row-deltas of 16 keep the XOR term invariant)
    const int aoff = (((wr * 128 + l15) * 64 + l4 * 16)) ^ (((l15 >> 1) & 3) << 4);
    const int boff = (((wc * 64 + l15) * 64 + l4 * 16)) ^ (((l15 >> 1) & 3) << 4);

    f32x4 acc[8][4];
    #pragma unroll
    for (int mi = 0; mi < 8; ++mi)
        #pragma unroll
        for (int ni = 0; ni < 4; ++ni)
            acc[mi][ni] = (f32x4){0.f, 0.f, 0.f, 0.f};

    auto stage = [&](int g) {               // g = ct*16 + kk, slot g&3
        const int kk = g & 15;
        const int ct = g >> 4;
        short* dst = &lds[(g & 3) * 16384];
        const int ao = kk * 32;
        const int bo = ct * 131072 + kk * 32;   // 256 cols * 512 shorts per col-tile
        #pragma unroll
        for (int c = 0; c < 2; ++c) {
            int q = c * 512 + tid;
            __builtin_amdgcn_global_load_lds(
                (const __attribute__((address_space(1))) uint32_t*)(const void*)(aSrc[c] + ao),
                (__attribute__((address_space(3))) uint32_t*)(dst + q * 8), 16, 0, 0);
            __builtin_amdgcn_global_load_lds(
                (const __attribute__((address_space(1))) uint32_t*)(const void*)(bSrc[c] + bo),
                (__attribute__((address_space(3))) uint32_t*)(dst + 8192 + q * 8), 16, 0, 0);
        }
    };

    auto rread = [&](int g, short8_t (&fa)[8], short8_t (&fb)[4]) {
        const char* base = (const char*)lds + (g & 3) * 32768;
        #pragma unroll
        for (int mi = 0; mi < 8; ++mi)
            fa[mi] = *(const short8_t*)(base + (aoff + mi * 1024));
        #pragma unroll
        for (int ni = 0; ni < 4; ++ni)
            fb[ni] = *(const short8_t*)(base + 16384 + (boff + ni * 1024));
    };

    auto mstep = [&](const short8_t (&fa)[8], const short8_t (&fb)[4]) {
        __builtin_amdgcn_s_setprio(1);
        #pragma unroll
        for (int mi = 0; mi < 8; ++mi)
            #pragma unroll
            for (int ni = 0; ni < 4; ++ni)
                acc[mi][ni] = __builtin_amdgcn_mfma_f32_16x16x32_bf16(
                    fa[mi], fb[ni], acc[mi][ni], 0, 0, 0);
        __builtin_amdgcn_s_setprio(0);
    };

    auto fold = [&](int ct) {   // per-col-tile argmax epilogue + acc reset
        float hn[4];
        #pragma unroll
        for (int ni = 0; ni < 4; ++ni)
            hn[ni] = cnhalf[colg0 + ct * 256 + wc * 64 + ni * 16 + l15];
        #pragma unroll
        for (int mi = 0; mi < 8; ++mi) {
            #pragma unroll
            for (int reg = 0; reg < 4; ++reg) {
                unsigned long long pk = 0ull;
                #pragma unroll
                for (int ni = 0; ni < 4; ++ni) {
                    float sc = acc[mi][ni][reg] - hn[ni];
                    uint32_t col = (uint32_t)(colg0 + ct * 256 + wc * 64 + ni * 16 + l15);
                    unsigned long long p =
                        ((unsigned long long)sortable_key(sc) << 32) | (uint32_t)(~col);
                    pk = (p > pk) ? p : pk;
                }
                #pragma unroll
                for (int off = 1; off < 16; off <<= 1) {
                    unsigned long long q = __shfl_xor(pk, off);
                    pk = (q > pk) ? q : pk;
                }
                if (l15 == 0) {
                    int row = row0 + wr * 128 + mi * 16 + l4 * 4 + reg;
                    atomicMax(&best[row], pk);
                }
            }
        }
        #pragma unroll
        for (int mi = 0; mi < 8; ++mi)
            #pragma unroll
            for (int ni = 0; ni < 4; ++ni)
                acc[mi][ni] = (f32x4){0.f, 0.f, 0.f, 0.f};
    };

    short8_t fa0[8], fb0[4], fa1[8], fb1[4];

    // prologue
    stage(0); stage(1); stage(2);
    WAITV8();            // stage(0) landed (mine); barrier makes it global
    LGKM0();
    BAR();
    rread(0, fa0, fb0);

    // main loop: two steps per iteration (static frag-buffer parity)
    #pragma unroll 1
    for (int gg = 0; gg < 60; gg += 2) {
        // even step g = gg: compute with (fa0,fb0), prefetch frags g+1 into (fa1,fb1)
        stage(gg + 3);
        WAITV8();        // stage(gg+1) landed
        LGKM0();         // my older ds_reads drained (slot-reuse proof)
        BAR();
        rread(gg + 1, fa1, fb1);
        mstep(fa0, fb0);
        // odd step g = gg+1
        stage(gg + 4);
        WAITV8();        // stage(gg+2) landed
        LGKM0();
        BAR();
        rread(gg + 2, fa0, fb0);
        mstep(fa1, fb1);
        if (((gg + 1) & 15) == 15) fold((gg + 1) >> 4);   // g = 15, 31, 47
    }
    // tail: g = 60..63  (stages 0..62 issued; 63 here)
    stage(63);
    WAITV8();  LGKM0();  BAR();
    rread(61, fa1, fb1);
    mstep(fa0, fb0);                 // g=60
    WAITV4();  LGKM0();  BAR();
    rread(62, fa0, fb0);
    mstep(fa1, fb1);                 // g=61
    WAITV0();  LGKM0();  BAR();
    rread(63, fa1, fb1);
    mstep(fa0, fb0);                 // g=62
    mstep(fa1, fb1);                 // g=63
    fold(3);
}

// ---------------- gather: contiguous BT row, loss partials, histogram ----------------
__global__ __launch_bounds__(256) void vq_gather(
        const float* __restrict__ x, const short* __restrict__ BT,
        const unsigned long long* __restrict__ best,
        float* __restrict__ out, unsigned int* __restrict__ count,
        float* __restrict__ lpart) {
    __shared__ float ls[4];
    const int lane = threadIdx.x & 63;
    const int w = threadIdx.x >> 6;
    const int r = blockIdx.x * 4 + w;

    unsigned long long v = best[r];
    const int idx = (int)(~(unsigned int)v) & (K_CODES - 1);

    short8_t hi = *(const short8_t*)&BT[(size_t)idx * 512 + lane * 8];
    float q[8];
    #pragma unroll
    for (int j = 0; j < 8; ++j) q[j] = bf16_to_f32(hi[j]);

    float4 xv0 = *(const float4*)&x[(size_t)r * C_DIM + lane * 8];
    float4 xv1 = *(const float4*)&x[(size_t)r * C_DIM + lane * 8 + 4];
    float xs[8] = {xv0.x, xv0.y, xv0.z, xv0.w, xv1.x, xv1.y, xv1.z, xv1.w};
    float s = 0.f;
    #pragma unroll
    for (int j = 0; j < 8; ++j) { float d = q[j] - xs[j]; s = fmaf(d, d, s); }
    float4 o0 = {q[0], q[1], q[2], q[3]}, o1 = {q[4], q[5], q[6], q[7]};
    *(float4*)&out[(size_t)r * C_DIM + lane * 8]     = o0;
    *(float4*)&out[(size_t)r * C_DIM + lane * 8 + 4] = o1;

    #pragma unroll
    for (int off = 32; off > 0; off >>= 1) s += __shfl_down(s, off);
    if (lane == 0) { ls[w] = s; atomicAdd(&count[idx], 1u); }
    __syncthreads();
    if (threadIdx.x == 0) lpart[blockIdx.x] = ls[0] + ls[1] + ls[2] + ls[3];
}

// ---------------- finalize: loss + perplexity ----------------
__global__ __launch_bounds__(256) void vq_finalize(
        const float* __restrict__ running, const unsigned int* __restrict__ count,
        const float* __restrict__ lpart, float* __restrict__ out) {
    __shared__ float sh[256];
    const int tid = threadIdx.x;

    float s = 0.f;
    for (int i = tid; i < 2048; i += 256) s += lpart[i];
    sh[tid] = s; __syncthreads();
    for (int st = 128; st > 0; st >>= 1) {
        if (tid < st) sh[tid] += sh[tid + st];
        __syncthreads();
    }
    if (tid == 0) out[(size_t)M_ROWS * C_DIM] = 1.25f * sh[0] / (float)(M_ROWS * C_DIM);
    __syncthreads();

    float s2 = 0.f;
    for (int k = tid; k < K_CODES; k += 256) {
        float p = 0.9f * running[k] + 0.1f * ((float)count[k] * (1.0f / (float)M_ROWS));
        s2 += p * logf(p + 1e-10f);
    }
    sh[tid] = s2; __syncthreads();
    for (int st = 128; st > 0; st >>= 1) {
        if (tid < st) sh[tid] += sh[tid + st];
        __syncthreads();
    }
    if (tid == 0) out[(size_t)M_ROWS * C_DIM + 1] = expf(-sh[0]);
}

extern "C" void kernel_launch(void* const* d_in, const int* in_sizes, int n_in,
                              void* d_out, int out_size, void* d_ws, size_t ws_size,
                              hipStream_t stream) {
    const float* x       = (const float*)d_in[0];
    const float* emb     = (const float*)d_in[1];
    const float* running = (const float*)d_in[2];
    float* out = (float*)d_out;
    char* ws = (char*)d_ws;

    unsigned long long* best = (unsigned long long*)(ws + WS_BEST);
    float*        cnhalf = (float*)(ws + WS_CNHALF);
    unsigned int* count  = (unsigned int*)(ws + WS_COUNT);
    float*        lpart  = (float*)(ws + WS_LPART);
    short*        A2     = (short*)(ws + WS_A2);
    short*        BT     = (short*)(ws + WS_BT);

    vq_prep<<<5152, 256, 0, stream>>>(x, emb, A2, BT, cnhalf, (unsigned long long*)ws);
    vq_mfma_argmax<<<dim3(K_CODES / 1024, M_ROWS / 256), 512, 0, stream>>>(A2, BT, cnhalf, best);
    vq_gather<<<M_ROWS / 4, 256, 0, stream>>>(x, BT, best, out, count, lpart);
    vq_finalize<<<1, 256, 0, stream>>>(running, count, lpart, out);
}

// Round 8
// 153.178 us; speedup vs baseline: 1.1794x; 1.1794x over previous
//
#include <hip/hip_runtime.h>
#include <stdint.h>

#define M_ROWS 8192
#define C_DIM  512
#define K_CODES 8192

// ws layout:
//   best   : u64[8192]       @ 0
//   cnhalf : f32[8192]       @ 65536
//   count  : u32[8192]       @ 98304
//   lpart  : f32[2048]       @ 131072     (zero region = 139264 B = 17408 u64)
//   A2     : bf16[8192][512] @ 1048576    (X_hi), 8 MB
//   BT     : bf16[8192][512] @ 9437184    (E^T_hi), 8 MB
#define WS_BEST     0
#define WS_CNHALF   65536
#define WS_COUNT    98304
#define WS_LPART    131072
#define WS_ZERO_U64 17408
#define WS_A2       1048576
#define WS_BT       9437184

typedef __attribute__((ext_vector_type(8))) short short8_t;
typedef __attribute__((ext_vector_type(4))) float f32x4;

__device__ __forceinline__ short f32_to_bf16_rne(float v) {
    uint32_t u = __float_as_uint(v);
    uint32_t r = (u + 0x7FFFu + ((u >> 16) & 1u)) >> 16;
    return (short)r;
}
__device__ __forceinline__ float bf16_to_f32(short s) {
    return __uint_as_float(((uint32_t)(uint16_t)s) << 16);
}
__device__ __forceinline__ uint32_t sortable_key(float f) {
    uint32_t b = __float_as_uint(f);
    return ((int)b >= 0) ? (b | 0x80000000u) : ~b;
}

// ---------------- prep: fused conv_x (+ws zero) | conv_e | colnorm ----------------
__global__ __launch_bounds__(256) void vq_prep(const float* __restrict__ x,
                                               const float* __restrict__ emb,
                                               short* __restrict__ A2,
                                               short* __restrict__ BT,
                                               float* __restrict__ cnhalf,
                                               unsigned long long* __restrict__ wszero) {
    __shared__ float t[64][65];
    const int bid = blockIdx.x;
    const int tid = threadIdx.x;
    if (bid < 4096) {
        int idx = bid * 256 + tid;
        if (idx < WS_ZERO_U64) wszero[idx] = 0ull;
        int m = idx >> 7;
        int c4 = (idx & 127) * 4;
        float4 v = *(const float4*)&x[(size_t)m * C_DIM + c4];
        short hi[4] = {f32_to_bf16_rne(v.x), f32_to_bf16_rne(v.y),
                       f32_to_bf16_rne(v.z), f32_to_bf16_rne(v.w)};
        *(short4*)&A2[(size_t)m * 512 + c4] = *(short4*)hi;
    } else if (bid < 5120) {
        int r = bid - 4096;
        int nb = (r & 127) * 64;
        int cb = (r >> 7) * 64;
        #pragma unroll
        for (int i = 0; i < 16; ++i) {
            int c = (tid >> 6) + i * 4;
            t[c][tid & 63] = emb[(size_t)(cb + c) * K_CODES + nb + (tid & 63)];
        }
        __syncthreads();
        const int n = tid >> 2;
        const int cp = (tid & 3) * 16;
        short hibuf[16];
        #pragma unroll
        for (int i = 0; i < 16; ++i) hibuf[i] = f32_to_bf16_rne(t[cp + i][n]);
        size_t base = (size_t)(nb + n) * 512 + cb + cp;
        *(short8_t*)&BT[base + 0] = *(short8_t*)&hibuf[0];
        *(short8_t*)&BT[base + 8] = *(short8_t*)&hibuf[8];
    } else {
        int k = (bid - 5120) * 256 + tid;
        float s = 0.f;
        for (int c = 0; c < C_DIM; ++c) {
            float v = emb[(size_t)c * K_CODES + k];
            s = fmaf(v, v, s);
        }
        cnhalf[k] = 0.5f * s;
    }
}

// ---------------- MFMA score GEMM: 256x1024 per block (4 col-tiles), 8 waves (2x4),
// per-wave 128x64, BK=32, ring-4 LDS, depth-3 counted vmcnt (R6-proven), with each
// K-step split into TWO template phases:
//   P1: {ds_read af0-3+fb0-3; stage A-half(g+3); BAR; lgkm0; prio1; 16 MFMA mi0-3; prio0; BAR}
//   P2: {ds_read af4-7;       stage B-half(g+3); WAITV(cnt); BAR; lgkm0; prio1; 16 MFMA mi4-7; prio0; BAR}
// vmcnt invariant: after stageB(g+3) outstanding = tiles g+1,g+2,g+3 (12) -> WAITV8
// drains tile g+1 (needed by step g+1's P1 reads). Tail: g=61 -> 4, g=62 -> 0.
// Slot-reuse: all tile-(g-1) reads drained at each phase's lgkm0 before the final BAR
// preceding any stage(g+3) issue (slot (g+3)&3 == (g-1)&3).
// LDS 16B-slot swizzle (R4-R6 verified, 0 conflicts): q = (row*4+s) ^ ((row>>1)&3);
// inverse on global source: row = q>>2, s = (q&3)^((q>>3)&3).
#define WAITV8() asm volatile("s_waitcnt vmcnt(8)" ::: "memory")
#define WAITV4() asm volatile("s_waitcnt vmcnt(4)" ::: "memory")
#define WAITV0() asm volatile("s_waitcnt vmcnt(0)" ::: "memory")
#define LGKM0()  asm volatile("s_waitcnt lgkmcnt(0)" ::: "memory")
#define BAR()    __builtin_amdgcn_s_barrier()

__global__ __launch_bounds__(512, 2) void vq_mfma_argmax(
        const short* __restrict__ A2, const short* __restrict__ BT,
        const float* __restrict__ cnhalf, unsigned long long* __restrict__ best) {
    __shared__ short lds[65536];   // 4 slots x (A[256][32] | B[256][32]) = 128 KiB

    const int tid  = threadIdx.x;
    const int lane = tid & 63;
    const int w    = tid >> 6;
    const int wr   = w >> 2;        // 0..1: 128-row half
    const int wc   = w & 3;         // 0..3: 64-col quarter
    const int l15  = lane & 15;
    const int l4   = lane >> 4;

    const int colg0 = blockIdx.x * 1024;  // blk%8 == col-group -> B-panel pinned per XCD L2
    const int row0  = blockIdx.y * 256;

    // staging source pointers (inverse-swizzled)
    const short* aSrc[2];
    const short* bSrc[2];
    #pragma unroll
    for (int c = 0; c < 2; ++c) {
        int q = c * 512 + tid;
        int row = q >> 2;
        int s = (q & 3) ^ ((q >> 3) & 3);
        aSrc[c] = A2 + (size_t)(row0 + row) * 512 + s * 8;
        bSrc[c] = BT + (size_t)(colg0 + row) * 512 + s * 8;
    }

    // swizzled ds_read byte offsets (row-deltas of 16 keep the XOR term invariant)
    const int aoff = (((wr * 128 + l15) * 64 + l4 * 16)) ^ (((l15 >> 1) & 3) << 4);
    const int boff = (((wc * 64 + l15) * 64 + l4 * 16)) ^ (((l15 >> 1) & 3) << 4);

    // preload all half-norms, retire them before staging starts (clean vmcnt ladder)
    float hn[4][4];
    #pragma unroll
    for (int ct = 0; ct < 4; ++ct)
        #pragma unroll
        for (int ni = 0; ni < 4; ++ni)
            hn[ct][ni] = cnhalf[colg0 + ct * 256 + wc * 64 + ni * 16 + l15];
    WAITV0();

    auto stageA = [&](int g) {               // A-half of tile g, slot g&3 (2 loads)
        const int kk = g & 15;
        short* dst = &lds[(g & 3) * 16384];
        const int ao = kk * 32;
        #pragma unroll
        for (int c = 0; c < 2; ++c) {
            int q = c * 512 + tid;
            __builtin_amdgcn_global_load_lds(
                (const __attribute__((address_space(1))) uint32_t*)(const void*)(aSrc[c] + ao),
                (__attribute__((address_space(3))) uint32_t*)(dst + q * 8), 16, 0, 0);
        }
    };
    auto stageB = [&](int g) {               // B-half of tile g (2 loads)
        const int kk = g & 15;
        const int ct2 = g >> 4;
        short* dst = &lds[(g & 3) * 16384];
        const int bo = ct2 * 131072 + kk * 32;   // 256 cols * 512 shorts per col-tile
        #pragma unroll
        for (int c = 0; c < 2; ++c) {
            int q = c * 512 + tid;
            __builtin_amdgcn_global_load_lds(
                (const __attribute__((address_space(1))) uint32_t*)(const void*)(bSrc[c] + bo),
                (__attribute__((address_space(3))) uint32_t*)(dst + 8192 + q * 8), 16, 0, 0);
        }
    };

    f32x4 acc[8][4];

    // prologue: tiles 0,1,2 in flight; tile 0 landed before first reads
    stageA(0); stageB(0);
    stageA(1); stageB(1);
    stageA(2); stageB(2);
    WAITV8();
    BAR();

    #pragma unroll
    for (int ct = 0; ct < 4; ++ct) {
        #pragma unroll
        for (int mi = 0; mi < 8; ++mi)
            #pragma unroll
            for (int ni = 0; ni < 4; ++ni)
                acc[mi][ni] = (f32x4){0.f, 0.f, 0.f, 0.f};

        #pragma unroll 1
        for (int k = 0; k < 16; ++k) {
            const int g = ct * 16 + k;
            const char* base = (const char*)lds + (g & 3) * 32768;

            // ---- phase 1: frag reads (8) + A-half stage + 16 MFMA (mi 0-3) ----
            short8_t af[4], fb[4];
            #pragma unroll
            for (int mi = 0; mi < 4; ++mi)
                af[mi] = *(const short8_t*)(base + (aoff + mi * 1024));
            #pragma unroll
            for (int ni = 0; ni < 4; ++ni)
                fb[ni] = *(const short8_t*)(base + 16384 + (boff + ni * 1024));
            if (g <= 60) stageA(g + 3);
            BAR();
            LGKM0();
            __builtin_amdgcn_s_setprio(1);
            #pragma unroll
            for (int mi = 0; mi < 4; ++mi)
                #pragma unroll
                for (int ni = 0; ni < 4; ++ni)
                    acc[mi][ni] = __builtin_amdgcn_mfma_f32_16x16x32_bf16(
                        af[mi], fb[ni], acc[mi][ni], 0, 0, 0);
            __builtin_amdgcn_s_setprio(0);
            BAR();

            // ---- phase 2: frag reads (4) + B-half stage + counted vmcnt + 16 MFMA (mi 4-7) ----
            short8_t ag[4];
            #pragma unroll
            for (int mi = 0; mi < 4; ++mi)
                ag[mi] = *(const short8_t*)(base + (aoff + (4 + mi) * 1024));
            if (g <= 60) stageB(g + 3);
            if (g < 61)      { WAITV8(); }
            else if (g == 61){ WAITV4(); }
            else if (g == 62){ WAITV0(); }
            BAR();
            LGKM0();
            __builtin_amdgcn_s_setprio(1);
            #pragma unroll
            for (int mi = 0; mi < 4; ++mi)
                #pragma unroll
                for (int ni = 0; ni < 4; ++ni)
                    acc[4 + mi][ni] = __builtin_amdgcn_mfma_f32_16x16x32_bf16(
                        ag[mi], fb[ni], acc[4 + mi][ni], 0, 0, 0);
            __builtin_amdgcn_s_setprio(0);
            BAR();
        }

        // per-col-tile argmax epilogue (ct static: hn[ct] is register-indexed)
        #pragma unroll
        for (int mi = 0; mi < 8; ++mi) {
            #pragma unroll
            for (int reg = 0; reg < 4; ++reg) {
                unsigned long long pk = 0ull;
                #pragma unroll
                for (int ni = 0; ni < 4; ++ni) {
                    float sc = acc[mi][ni][reg] - hn[ct][ni];
                    uint32_t col = (uint32_t)(colg0 + ct * 256 + wc * 64 + ni * 16 + l15);
                    unsigned long long p =
                        ((unsigned long long)sortable_key(sc) << 32) | (uint32_t)(~col);
                    pk = (p > pk) ? p : pk;
                }
                #pragma unroll
                for (int off = 1; off < 16; off <<= 1) {
                    unsigned long long q = __shfl_xor(pk, off);
                    pk = (q > pk) ? q : pk;
                }
                if (l15 == 0) {
                    int row = row0 + wr * 128 + mi * 16 + l4 * 4 + reg;
                    atomicMax(&best[row], pk);
                }
            }
        }
    }
}

// ---------------- gather: contiguous BT row, loss partials, histogram ----------------
__global__ __launch_bounds__(256) void vq_gather(
        const float* __restrict__ x, const short* __restrict__ BT,
        const unsigned long long* __restrict__ best,
        float* __restrict__ out, unsigned int* __restrict__ count,
        float* __restrict__ lpart) {
    __shared__ float ls[4];
    const int lane = threadIdx.x & 63;
    const int w = threadIdx.x >> 6;
    const int r = blockIdx.x * 4 + w;

    unsigned long long v = best[r];
    const int idx = (int)(~(unsigned int)v) & (K_CODES - 1);

    short8_t hi = *(const short8_t*)&BT[(size_t)idx * 512 + lane * 8];
    float q[8];
    #pragma unroll
    for (int j = 0; j < 8; ++j) q[j] = bf16_to_f32(hi[j]);

    float4 xv0 = *(const float4*)&x[(size_t)r * C_DIM + lane * 8];
    float4 xv1 = *(const float4*)&x[(size_t)r * C_DIM + lane * 8 + 4];
    float xs[8] = {xv0.x, xv0.y, xv0.z, xv0.w, xv1.x, xv1.y, xv1.z, xv1.w};
    float s = 0.f;
    #pragma unroll
    for (int j = 0; j < 8; ++j) { float d = q[j] - xs[j]; s = fmaf(d, d, s); }
    float4 o0 = {q[0], q[1], q[2], q[3]}, o1 = {q[4], q[5], q[6], q[7]};
    *(float4*)&out[(size_t)r * C_DIM + lane * 8]     = o0;
    *(float4*)&out[(size_t)r * C_DIM + lane * 8 + 4] = o1;

    #pragma unroll
    for (int off = 32; off > 0; off >>= 1) s += __shfl_down(s, off);
    if (lane == 0) { ls[w] = s; atomicAdd(&count[idx], 1u); }
    __syncthreads();
    if (threadIdx.x == 0) lpart[blockIdx.x] = ls[0] + ls[1] + ls[2] + ls[3];
}

// ---------------- finalize: loss + perplexity ----------------
__global__ __launch_bounds__(256) void vq_finalize(
        const float* __restrict__ running, const unsigned int* __restrict__ count,
        const float* __restrict__ lpart, float* __restrict__ out) {
    __shared__ float sh[256];
    const int tid = threadIdx.x;

    float s = 0.f;
    for (int i = tid; i < 2048; i += 256) s += lpart[i];
    sh[tid] = s; __syncthreads();
    for (int st = 128; st > 0; st >>= 1) {
        if (tid < st) sh[tid] += sh[tid + st];
        __syncthreads();
    }
    if (tid == 0) out[(size_t)M_ROWS * C_DIM] = 1.25f * sh[0] / (float)(M_ROWS * C_DIM);
    __syncthreads();

    float s2 = 0.f;
    for (int k = tid; k < K_CODES; k += 256) {
        float p = 0.9f * running[k] + 0.1f * ((float)count[k] * (1.0f / (float)M_ROWS));
        s2 += p * logf(p + 1e-10f);
    }
    sh[tid] = s2; __syncthreads();
    for (int st = 128; st > 0; st >>= 1) {
        if (tid < st) sh[tid] += sh[tid + st];
        __syncthreads();
    }
    if (tid == 0) out[(size_t)M_ROWS * C_DIM + 1] = expf(-sh[0]);
}

extern "C" void kernel_launch(void* const* d_in, const int* in_sizes, int n_in,
                              void* d_out, int out_size, void* d_ws, size_t ws_size,
                              hipStream_t stream) {
    const float* x       = (const float*)d_in[0];
    const float* emb     = (const float*)d_in[1];
    const float* running = (const float*)d_in[2];
    float* out = (float*)d_out;
    char* ws = (char*)d_ws;

    unsigned long long* best = (unsigned long long*)(ws + WS_BEST);
    float*        cnhalf = (float*)(ws + WS_CNHALF);
    unsigned int* count  = (unsigned int*)(ws + WS_COUNT);
    float*        lpart  = (float*)(ws + WS_LPART);
    short*        A2     = (short*)(ws + WS_A2);
    short*        BT     = (short*)(ws + WS_BT);

    vq_prep<<<5152, 256, 0, stream>>>(x, emb, A2, BT, cnhalf, (unsigned long long*)ws);
    vq_mfma_argmax<<<dim3(K_CODES / 1024, M_ROWS / 256), 512, 0, stream>>>(A2, BT, cnhalf, best);
    vq_gather<<<M_ROWS / 4, 256, 0, stream>>>(x, BT, best, out, count, lpart);
    vq_finalize<<<1, 256, 0, stream>>>(running, count, lpart, out);
}